// Round 1
// baseline (385.585 us; speedup 1.0000x reference)
//
#include <hip/hip_runtime.h>

#define HW 16384   // 128*128
#define NC 256     // C
#define NB 16      // B

// ---------------------------------------------------------------------------
// Kernel 1: global average pool over H*W for both tensors.
// One block per (tensor, b, c): 2*16*256 = 8192 blocks, 256 threads each.
// Each block sums 16384 floats via 16 coalesced float4 loads/thread.
// pooled layout: [b][0..255]=fft means, [b][256..511]=multi means  -> [16][512]
// ---------------------------------------------------------------------------
__global__ __launch_bounds__(256) void pool_kernel(const float* __restrict__ fft,
                                                   const float* __restrict__ multi,
                                                   float* __restrict__ pooled) {
    int idx = blockIdx.x;            // 0..8191
    int tensor = idx >> 12;          // 0=fft, 1=multi
    int bc = idx & 4095;             // b*256 + c
    const float* src = (tensor ? multi : fft) + (size_t)bc * HW;
    const float4* src4 = (const float4*)src;
    int tid = threadIdx.x;

    float sum = 0.f;
#pragma unroll
    for (int it = 0; it < 16; ++it) {
        float4 v = src4[it * 256 + tid];   // fully coalesced, 1KB/wave/inst
        sum += (v.x + v.y) + (v.z + v.w);
    }
    // wave64 shuffle reduce
#pragma unroll
    for (int off = 32; off > 0; off >>= 1) sum += __shfl_down(sum, off, 64);

    __shared__ float ws[4];
    int lane = tid & 63, wid = tid >> 6;
    if (lane == 0) ws[wid] = sum;
    __syncthreads();
    if (tid == 0) {
        float s = (ws[0] + ws[1]) + (ws[2] + ws[3]);
        int b = bc >> 8, c = bc & 255;
        pooled[b * 512 + tensor * 256 + c] = s * (1.0f / HW);
    }
}

// ---------------------------------------------------------------------------
// Kernel 2: the tiny MLP. h = relu(pooled @ w1^T) [16x64],
// attn = sigmoid(h @ w2^T) [16x512]. ~1 MFLOP -> one block, 512 threads.
// w1: [64][512] row-major (h[b][r] = sum_c pooled[b][c]*w1[r][c])
// w2: [512][64] row-major (attn[b][c] = sum_r h[b][r]*w2[c][r])
// ---------------------------------------------------------------------------
__global__ __launch_bounds__(512) void mlp_kernel(const float* __restrict__ pooled,
                                                  const float* __restrict__ w1,
                                                  const float* __restrict__ w2,
                                                  float* __restrict__ attn) {
    __shared__ float h[NB][64];
    int tid = threadIdx.x;

    // 16*64 = 1024 h-values, 2 per thread; dot length 512
    for (int i = tid; i < NB * 64; i += 512) {
        int b = i >> 6, r = i & 63;
        const float* p = pooled + b * 512;
        const float* w = w1 + (size_t)r * 512;
        float s = 0.f;
#pragma unroll 8
        for (int k = 0; k < 512; ++k) s = fmaf(p[k], w[k], s);
        h[b][r] = fmaxf(s, 0.f);
    }
    __syncthreads();

    // 16*512 = 8192 attn-values, 16 per thread; dot length 64
    for (int i = tid; i < NB * 512; i += 512) {
        int b = i >> 9, c = i & 511;
        const float* w = w2 + (size_t)c * 64;
        const float* hh = &h[b][0];
        float s = 0.f;
#pragma unroll 8
        for (int k = 0; k < 64; ++k) s = fmaf(hh[k], w[k], s);
        attn[b * 512 + c] = 1.0f / (1.0f + __expf(-s));
    }
}

// ---------------------------------------------------------------------------
// Kernel 3: out = attn[b][c]*fft + attn[b][256+c]*multi, float4 grid-stride.
// One (b,c) plane = 16384 elems = 4096 float4s -> plane id = i4 >> 12.
// ---------------------------------------------------------------------------
__global__ __launch_bounds__(256) void apply_kernel(const float* __restrict__ fft,
                                                    const float* __restrict__ multi,
                                                    const float* __restrict__ attn,
                                                    float* __restrict__ out) {
    const float4* f4 = (const float4*)fft;
    const float4* m4 = (const float4*)multi;
    float4* o4 = (float4*)out;
    const size_t total4 = (size_t)NB * NC * HW / 4;  // 16,777,216
    size_t stride = (size_t)gridDim.x * blockDim.x;
    for (size_t i = (size_t)blockIdx.x * blockDim.x + threadIdx.x; i < total4; i += stride) {
        int plane = (int)(i >> 12);          // b*256 + c
        int b = plane >> 8, c = plane & 255;
        float fw = attn[b * 512 + c];
        float mw = attn[b * 512 + 256 + c];
        float4 f = f4[i];
        float4 m = m4[i];
        float4 o;
        o.x = fmaf(fw, f.x, mw * m.x);
        o.y = fmaf(fw, f.y, mw * m.y);
        o.z = fmaf(fw, f.z, mw * m.z);
        o.w = fmaf(fw, f.w, mw * m.w);
        o4[i] = o;
    }
}

extern "C" void kernel_launch(void* const* d_in, const int* in_sizes, int n_in,
                              void* d_out, int out_size, void* d_ws, size_t ws_size,
                              hipStream_t stream) {
    const float* fft   = (const float*)d_in[0];
    const float* multi = (const float*)d_in[1];
    const float* w1    = (const float*)d_in[2];   // [64][512]
    const float* w2    = (const float*)d_in[3];   // [512][64]
    float* out = (float*)d_out;

    float* pooled = (float*)d_ws;                 // [16][512] = 8192 floats
    float* attn   = pooled + NB * 512;            // [16][512]

    pool_kernel<<<2 * NB * NC, 256, 0, stream>>>(fft, multi, pooled);
    mlp_kernel<<<1, 512, 0, stream>>>(pooled, w1, w2, attn);
    apply_kernel<<<2048, 256, 0, stream>>>(fft, multi, attn, out);
}

// Round 2
// 263.812 us; speedup vs baseline: 1.4616x; 1.4616x over previous
//
#include <hip/hip_runtime.h>

#define HW 16384   // 128*128
#define NC 256     // C
#define NB 16      // B

// ---------------------------------------------------------------------------
// Kernel 1: global average pool over H*W for both tensors.
// One block per (tensor, b, c): 2*16*256 = 8192 blocks, 256 threads each.
// 16 float4 loads/thread in two batches of 8 NAMED registers with 8
// independent accumulators -> 8 loads in flight per wave (was ~4 at VGPR=32).
// pooled layout: [b][0..255]=fft means, [b][256..511]=multi means  -> [16][512]
// ---------------------------------------------------------------------------
__global__ __launch_bounds__(256) void pool_kernel(const float* __restrict__ fft,
                                                   const float* __restrict__ multi,
                                                   float* __restrict__ pooled) {
    int idx = blockIdx.x;            // 0..8191
    int tensor = idx >> 12;          // 0=fft, 1=multi
    int bc = idx & 4095;             // b*256 + c
    const float4* src4 = (const float4*)((tensor ? multi : fft) + (size_t)bc * HW);
    int tid = threadIdx.x;

    float s0 = 0.f, s1 = 0.f, s2 = 0.f, s3 = 0.f;
    float s4 = 0.f, s5 = 0.f, s6 = 0.f, s7 = 0.f;
#pragma unroll
    for (int half = 0; half < 2; ++half) {
        const float4* p = src4 + half * 2048 + tid;
        float4 v0 = p[0];
        float4 v1 = p[256];
        float4 v2 = p[512];
        float4 v3 = p[768];
        float4 v4 = p[1024];
        float4 v5 = p[1280];
        float4 v6 = p[1536];
        float4 v7 = p[1792];
        s0 += (v0.x + v0.y) + (v0.z + v0.w);
        s1 += (v1.x + v1.y) + (v1.z + v1.w);
        s2 += (v2.x + v2.y) + (v2.z + v2.w);
        s3 += (v3.x + v3.y) + (v3.z + v3.w);
        s4 += (v4.x + v4.y) + (v4.z + v4.w);
        s5 += (v5.x + v5.y) + (v5.z + v5.w);
        s6 += (v6.x + v6.y) + (v6.z + v6.w);
        s7 += (v7.x + v7.y) + (v7.z + v7.w);
    }
    float sum = ((s0 + s1) + (s2 + s3)) + ((s4 + s5) + (s6 + s7));

    // wave64 butterfly reduce
#pragma unroll
    for (int off = 32; off > 0; off >>= 1) sum += __shfl_xor(sum, off, 64);

    __shared__ float ws[4];
    int lane = tid & 63, wid = tid >> 6;
    if (lane == 0) ws[wid] = sum;
    __syncthreads();
    if (tid == 0) {
        float s = (ws[0] + ws[1]) + (ws[2] + ws[3]);
        int b = bc >> 8, c = bc & 255;
        pooled[b * 512 + tensor * 256 + c] = s * (1.0f / HW);
    }
}

// ---------------------------------------------------------------------------
// Kernel 2a: h[b][r] = relu(sum_c pooled[b][c] * w1[r][c]),  w1: [64][512]
// One wave per output (1024 outputs -> 256 blocks x 256 threads).
// Lane l reads w1[r][8l..8l+7] (coalesced float4 x2) + matching pooled slice.
// ---------------------------------------------------------------------------
__global__ __launch_bounds__(256) void mlp1_kernel(const float* __restrict__ pooled,
                                                   const float* __restrict__ w1,
                                                   float* __restrict__ h) {
    int wid = (blockIdx.x << 2) | (threadIdx.x >> 6);   // 0..1023
    int lane = threadIdx.x & 63;
    int b = wid >> 6, r = wid & 63;
    const float4* w = (const float4*)(w1 + (size_t)r * 512) + (lane << 1);
    const float4* p = (const float4*)(pooled + b * 512) + (lane << 1);
    float4 wa = w[0], wb = w[1];
    float4 pa = p[0], pb = p[1];
    float s = wa.x * pa.x + wa.y * pa.y + wa.z * pa.z + wa.w * pa.w
            + wb.x * pb.x + wb.y * pb.y + wb.z * pb.z + wb.w * pb.w;
#pragma unroll
    for (int off = 32; off > 0; off >>= 1) s += __shfl_xor(s, off, 64);
    if (lane == 0) h[wid] = fmaxf(s, 0.f);
}

// ---------------------------------------------------------------------------
// Kernel 2b: attn[b][c] = sigmoid(sum_r h[b][r] * w2[c][r]),  w2: [512][64]
// One wave per output (8192 outputs -> 2048 blocks x 256 threads).
// Lane r reads w2[c][r] (coalesced) and h[b][r] (L2-resident, 4 KB total).
// ---------------------------------------------------------------------------
__global__ __launch_bounds__(256) void mlp2_kernel(const float* __restrict__ h,
                                                   const float* __restrict__ w2,
                                                   float* __restrict__ attn) {
    int wid = (blockIdx.x << 2) | (threadIdx.x >> 6);   // 0..8191
    int lane = threadIdx.x & 63;
    int b = wid >> 9, c = wid & 511;
    float s = h[(b << 6) | lane] * w2[((size_t)c << 6) | lane];
#pragma unroll
    for (int off = 32; off > 0; off >>= 1) s += __shfl_xor(s, off, 64);
    if (lane == 0) attn[(b << 9) | c] = 1.0f / (1.0f + __expf(-s));
}

// ---------------------------------------------------------------------------
// Kernel 3: out = attn[b][c]*fft + attn[b][256+c]*multi, float4 grid-stride.
// One (b,c) plane = 16384 elems = 4096 float4s -> plane id = i4 >> 12.
// ---------------------------------------------------------------------------
__global__ __launch_bounds__(256) void apply_kernel(const float* __restrict__ fft,
                                                    const float* __restrict__ multi,
                                                    const float* __restrict__ attn,
                                                    float* __restrict__ out) {
    const float4* f4 = (const float4*)fft;
    const float4* m4 = (const float4*)multi;
    float4* o4 = (float4*)out;
    const size_t total4 = (size_t)NB * NC * HW / 4;  // 16,777,216
    size_t stride = (size_t)gridDim.x * blockDim.x;
    for (size_t i = (size_t)blockIdx.x * blockDim.x + threadIdx.x; i < total4; i += stride) {
        int plane = (int)(i >> 12);          // b*256 + c
        int b = plane >> 8, c = plane & 255;
        float fw = attn[b * 512 + c];
        float mw = attn[b * 512 + 256 + c];
        float4 f = f4[i];
        float4 m = m4[i];
        float4 o;
        o.x = fmaf(fw, f.x, mw * m.x);
        o.y = fmaf(fw, f.y, mw * m.y);
        o.z = fmaf(fw, f.z, mw * m.z);
        o.w = fmaf(fw, f.w, mw * m.w);
        o4[i] = o;
    }
}

extern "C" void kernel_launch(void* const* d_in, const int* in_sizes, int n_in,
                              void* d_out, int out_size, void* d_ws, size_t ws_size,
                              hipStream_t stream) {
    const float* fft   = (const float*)d_in[0];
    const float* multi = (const float*)d_in[1];
    const float* w1    = (const float*)d_in[2];   // [64][512]
    const float* w2    = (const float*)d_in[3];   // [512][64]
    float* out = (float*)d_out;

    float* pooled = (float*)d_ws;                 // [16][512] = 8192 floats
    float* h      = pooled + NB * 512;            // [16][64]  = 1024 floats
    float* attn   = h + NB * 64;                  // [16][512] = 8192 floats

    pool_kernel<<<2 * NB * NC, 256, 0, stream>>>(fft, multi, pooled);
    mlp1_kernel<<<256, 256, 0, stream>>>(pooled, w1, h);
    mlp2_kernel<<<2048, 256, 0, stream>>>(h, w2, attn);
    apply_kernel<<<2048, 256, 0, stream>>>(fft, multi, attn, out);
}

// Round 3
// 256.681 us; speedup vs baseline: 1.5022x; 1.0278x over previous
//
#include <hip/hip_runtime.h>

#define HW 16384   // 128*128
#define NC 256     // C
#define NB 16      // B

__device__ __forceinline__ float sum4(float4 v) { return (v.x + v.y) + (v.z + v.w); }

// ---------------------------------------------------------------------------
// Kernel 1: global average pool. 2048 blocks x 256 threads.
// Block g owns 4 consecutive planes (64 KB each) of ONE tensor:
//   g < 1024  -> fft planes  [4g, 4g+4)
//   g >= 1024 -> multi planes [4(g-1024), ...)
// Per plane: 16 named independent float4 loads per thread (the whole plane),
// 8 independent partial accumulators, wave shfl_xor reduce, LDS combine.
// __launch_bounds__(256,1) frees the register allocator so the 16-deep
// (x2 planes via unroll 2 -> 32-deep) load window actually stays in flight.
// ---------------------------------------------------------------------------
__global__ __launch_bounds__(256, 1) void pool_kernel(const float* __restrict__ fft,
                                                      const float* __restrict__ multi,
                                                      float* __restrict__ pooled) {
    int g = blockIdx.x;              // 0..2047
    int tensor = g >> 10;            // 0=fft, 1=multi
    int p0 = (g & 1023) << 2;        // first plane (bc) of this block's 4
    const float4* base = (const float4*)(tensor ? multi : fft) + ((size_t)p0 << 12);
    int tid = threadIdx.x;
    int lane = tid & 63, wid = tid >> 6;

    __shared__ float ws[4][4];       // [wave][plane]

#pragma unroll 2
    for (int pl = 0; pl < 4; ++pl) {
        const float4* p = base + ((size_t)pl << 12) + tid;
        float4 v0  = p[0],    v1  = p[256],  v2  = p[512],  v3  = p[768];
        float4 v4  = p[1024], v5  = p[1280], v6  = p[1536], v7  = p[1792];
        float4 v8  = p[2048], v9  = p[2304], v10 = p[2560], v11 = p[2816];
        float4 v12 = p[3072], v13 = p[3328], v14 = p[3584], v15 = p[3840];
        float s0 = sum4(v0) + sum4(v8);
        float s1 = sum4(v1) + sum4(v9);
        float s2 = sum4(v2) + sum4(v10);
        float s3 = sum4(v3) + sum4(v11);
        float s4 = sum4(v4) + sum4(v12);
        float s5 = sum4(v5) + sum4(v13);
        float s6 = sum4(v6) + sum4(v14);
        float s7 = sum4(v7) + sum4(v15);
        float sum = ((s0 + s1) + (s2 + s3)) + ((s4 + s5) + (s6 + s7));
#pragma unroll
        for (int off = 32; off > 0; off >>= 1) sum += __shfl_xor(sum, off, 64);
        if (lane == 0) ws[wid][pl] = sum;
    }
    __syncthreads();
    if (tid < 4) {
        float s = (ws[0][tid] + ws[1][tid]) + (ws[2][tid] + ws[3][tid]);
        int bc = p0 + tid;
        int b = bc >> 8, c = bc & 255;
        pooled[b * 512 + tensor * 256 + c] = s * (1.0f / HW);
    }
}

// ---------------------------------------------------------------------------
// Kernel 2a: h[b][r] = relu(sum_c pooled[b][c] * w1[r][c]),  w1: [64][512]
// One wave per output (1024 outputs -> 256 blocks x 256 threads).
// ---------------------------------------------------------------------------
__global__ __launch_bounds__(256) void mlp1_kernel(const float* __restrict__ pooled,
                                                   const float* __restrict__ w1,
                                                   float* __restrict__ h) {
    int wid = (blockIdx.x << 2) | (threadIdx.x >> 6);   // 0..1023
    int lane = threadIdx.x & 63;
    int b = wid >> 6, r = wid & 63;
    const float4* w = (const float4*)(w1 + (size_t)r * 512) + (lane << 1);
    const float4* p = (const float4*)(pooled + b * 512) + (lane << 1);
    float4 wa = w[0], wb = w[1];
    float4 pa = p[0], pb = p[1];
    float s = wa.x * pa.x + wa.y * pa.y + wa.z * pa.z + wa.w * pa.w
            + wb.x * pb.x + wb.y * pb.y + wb.z * pb.z + wb.w * pb.w;
#pragma unroll
    for (int off = 32; off > 0; off >>= 1) s += __shfl_xor(s, off, 64);
    if (lane == 0) h[wid] = fmaxf(s, 0.f);
}

// ---------------------------------------------------------------------------
// Kernel 2b: attn[b][c] = sigmoid(sum_r h[b][r] * w2[c][r]),  w2: [512][64]
// One wave per output (8192 outputs -> 2048 blocks x 256 threads).
// ---------------------------------------------------------------------------
__global__ __launch_bounds__(256) void mlp2_kernel(const float* __restrict__ h,
                                                   const float* __restrict__ w2,
                                                   float* __restrict__ attn) {
    int wid = (blockIdx.x << 2) | (threadIdx.x >> 6);   // 0..8191
    int lane = threadIdx.x & 63;
    int b = wid >> 9, c = wid & 511;
    float s = h[(b << 6) | lane] * w2[((size_t)c << 6) | lane];
#pragma unroll
    for (int off = 32; off > 0; off >>= 1) s += __shfl_xor(s, off, 64);
    if (lane == 0) attn[(b << 9) | c] = 1.0f / (1.0f + __expf(-s));
}

// ---------------------------------------------------------------------------
// Kernel 3: out = attn[b][c]*fft + attn[b][256+c]*multi, float4 grid-stride.
// ---------------------------------------------------------------------------
__global__ __launch_bounds__(256) void apply_kernel(const float* __restrict__ fft,
                                                    const float* __restrict__ multi,
                                                    const float* __restrict__ attn,
                                                    float* __restrict__ out) {
    const float4* f4 = (const float4*)fft;
    const float4* m4 = (const float4*)multi;
    float4* o4 = (float4*)out;
    const size_t total4 = (size_t)NB * NC * HW / 4;  // 16,777,216
    size_t stride = (size_t)gridDim.x * blockDim.x;
    for (size_t i = (size_t)blockIdx.x * blockDim.x + threadIdx.x; i < total4; i += stride) {
        int plane = (int)(i >> 12);          // b*256 + c
        int b = plane >> 8, c = plane & 255;
        float fw = attn[b * 512 + c];
        float mw = attn[b * 512 + 256 + c];
        float4 f = f4[i];
        float4 m = m4[i];
        float4 o;
        o.x = fmaf(fw, f.x, mw * m.x);
        o.y = fmaf(fw, f.y, mw * m.y);
        o.z = fmaf(fw, f.z, mw * m.z);
        o.w = fmaf(fw, f.w, mw * m.w);
        o4[i] = o;
    }
}

extern "C" void kernel_launch(void* const* d_in, const int* in_sizes, int n_in,
                              void* d_out, int out_size, void* d_ws, size_t ws_size,
                              hipStream_t stream) {
    const float* fft   = (const float*)d_in[0];
    const float* multi = (const float*)d_in[1];
    const float* w1    = (const float*)d_in[2];   // [64][512]
    const float* w2    = (const float*)d_in[3];   // [512][64]
    float* out = (float*)d_out;

    float* pooled = (float*)d_ws;                 // [16][512]
    float* h      = pooled + NB * 512;            // [16][64]
    float* attn   = h + NB * 64;                  // [16][512]

    pool_kernel<<<2048, 256, 0, stream>>>(fft, multi, pooled);
    mlp1_kernel<<<256, 256, 0, stream>>>(pooled, w1, h);
    mlp2_kernel<<<2048, 256, 0, stream>>>(h, w2, attn);
    apply_kernel<<<2048, 256, 0, stream>>>(fft, multi, attn, out);
}

// Round 5
// 242.569 us; speedup vs baseline: 1.5896x; 1.0582x over previous
//
#include <hip/hip_runtime.h>

#define HW 16384   // 128*128
#define NC 256     // C
#define NB 16      // B

typedef float floatx4 __attribute__((ext_vector_type(4)));

__device__ __forceinline__ float sum4(floatx4 v) { return (v.x + v.y) + (v.z + v.w); }
__device__ __forceinline__ floatx4 ntload(const floatx4* p) {
    return __builtin_nontemporal_load(p);
}

// ---------------------------------------------------------------------------
// Kernel 1: global average pool. 4096 blocks x 256 threads.
// Block bc (= b*256+c) reads plane bc of BOTH tensors (two concurrent 64 KB
// sequential streams, same shape as the fast apply_kernel) with non-temporal
// float4 loads (streaming/evict-first path — these bytes are single-use here).
// 8-deep named load batches per tensor per half-plane; independent partial
// accumulators; one wave shfl_xor reduce per tensor; LDS combine.
// ---------------------------------------------------------------------------
__global__ __launch_bounds__(256, 4) void pool_kernel(const float* __restrict__ fft,
                                                      const float* __restrict__ multi,
                                                      float* __restrict__ pooled) {
    int bc = blockIdx.x;             // 0..4095 = b*256 + c
    int tid = threadIdx.x;
    int lane = tid & 63, wid = tid >> 6;
    const floatx4* fbase = (const floatx4*)fft + ((size_t)bc << 12) + tid;
    const floatx4* mbase = (const floatx4*)multi + ((size_t)bc << 12) + tid;

    float fs0 = 0.f, fs1 = 0.f, fs2 = 0.f, fs3 = 0.f;
    float fs4 = 0.f, fs5 = 0.f, fs6 = 0.f, fs7 = 0.f;
    float ms0 = 0.f, ms1 = 0.f, ms2 = 0.f, ms3 = 0.f;
    float ms4 = 0.f, ms5 = 0.f, ms6 = 0.f, ms7 = 0.f;

#pragma unroll
    for (int chunk = 0; chunk < 2; ++chunk) {
        const floatx4* pf = fbase + chunk * 2048;
        const floatx4* pm = mbase + chunk * 2048;
        floatx4 f0 = ntload(pf + 0),    f1 = ntload(pf + 256);
        floatx4 f2 = ntload(pf + 512),  f3 = ntload(pf + 768);
        floatx4 f4 = ntload(pf + 1024), f5 = ntload(pf + 1280);
        floatx4 f6 = ntload(pf + 1536), f7 = ntload(pf + 1792);
        floatx4 m0 = ntload(pm + 0),    m1 = ntload(pm + 256);
        floatx4 m2 = ntload(pm + 512),  m3 = ntload(pm + 768);
        floatx4 m4 = ntload(pm + 1024), m5 = ntload(pm + 1280);
        floatx4 m6 = ntload(pm + 1536), m7 = ntload(pm + 1792);
        fs0 += sum4(f0); fs1 += sum4(f1); fs2 += sum4(f2); fs3 += sum4(f3);
        fs4 += sum4(f4); fs5 += sum4(f5); fs6 += sum4(f6); fs7 += sum4(f7);
        ms0 += sum4(m0); ms1 += sum4(m1); ms2 += sum4(m2); ms3 += sum4(m3);
        ms4 += sum4(m4); ms5 += sum4(m5); ms6 += sum4(m6); ms7 += sum4(m7);
    }
    float fsum = ((fs0 + fs1) + (fs2 + fs3)) + ((fs4 + fs5) + (fs6 + fs7));
    float msum = ((ms0 + ms1) + (ms2 + ms3)) + ((ms4 + ms5) + (ms6 + ms7));

#pragma unroll
    for (int off = 32; off > 0; off >>= 1) {
        fsum += __shfl_xor(fsum, off, 64);
        msum += __shfl_xor(msum, off, 64);
    }

    __shared__ float ws[4][2];
    if (lane == 0) { ws[wid][0] = fsum; ws[wid][1] = msum; }
    __syncthreads();
    if (tid < 2) {
        float s = (ws[0][tid] + ws[1][tid]) + (ws[2][tid] + ws[3][tid]);
        int b = bc >> 8, c = bc & 255;
        pooled[b * 512 + tid * 256 + c] = s * (1.0f / HW);
    }
}

// ---------------------------------------------------------------------------
// Kernel 2a: h[b][r] = relu(sum_c pooled[b][c] * w1[r][c]),  w1: [64][512]
// One wave per output (1024 outputs -> 256 blocks x 256 threads).
// ---------------------------------------------------------------------------
__global__ __launch_bounds__(256) void mlp1_kernel(const float* __restrict__ pooled,
                                                   const float* __restrict__ w1,
                                                   float* __restrict__ h) {
    int wid = (blockIdx.x << 2) | (threadIdx.x >> 6);   // 0..1023
    int lane = threadIdx.x & 63;
    int b = wid >> 6, r = wid & 63;
    const float4* w = (const float4*)(w1 + (size_t)r * 512) + (lane << 1);
    const float4* p = (const float4*)(pooled + b * 512) + (lane << 1);
    float4 wa = w[0], wb = w[1];
    float4 pa = p[0], pb = p[1];
    float s = wa.x * pa.x + wa.y * pa.y + wa.z * pa.z + wa.w * pa.w
            + wb.x * pb.x + wb.y * pb.y + wb.z * pb.z + wb.w * pb.w;
#pragma unroll
    for (int off = 32; off > 0; off >>= 1) s += __shfl_xor(s, off, 64);
    if (lane == 0) h[wid] = fmaxf(s, 0.f);
}

// ---------------------------------------------------------------------------
// Kernel 2b: attn[b][c] = sigmoid(sum_r h[b][r] * w2[c][r]),  w2: [512][64]
// One wave per output (8192 outputs -> 2048 blocks x 256 threads).
// ---------------------------------------------------------------------------
__global__ __launch_bounds__(256) void mlp2_kernel(const float* __restrict__ h,
                                                   const float* __restrict__ w2,
                                                   float* __restrict__ attn) {
    int wid = (blockIdx.x << 2) | (threadIdx.x >> 6);   // 0..8191
    int lane = threadIdx.x & 63;
    int b = wid >> 9, c = wid & 511;
    float s = h[(b << 6) | lane] * w2[((size_t)c << 6) | lane];
#pragma unroll
    for (int off = 32; off > 0; off >>= 1) s += __shfl_xor(s, off, 64);
    if (lane == 0) attn[(b << 9) | c] = 1.0f / (1.0f + __expf(-s));
}

// ---------------------------------------------------------------------------
// Kernel 3: out = attn[b][c]*fft + attn[b][256+c]*multi, float4 grid-stride.
// (unchanged — it's the fastest kernel in the pipeline)
// ---------------------------------------------------------------------------
__global__ __launch_bounds__(256) void apply_kernel(const float* __restrict__ fft,
                                                    const float* __restrict__ multi,
                                                    const float* __restrict__ attn,
                                                    float* __restrict__ out) {
    const float4* f4 = (const float4*)fft;
    const float4* m4 = (const float4*)multi;
    float4* o4 = (float4*)out;
    const size_t total4 = (size_t)NB * NC * HW / 4;  // 16,777,216
    size_t stride = (size_t)gridDim.x * blockDim.x;
    for (size_t i = (size_t)blockIdx.x * blockDim.x + threadIdx.x; i < total4; i += stride) {
        int plane = (int)(i >> 12);          // b*256 + c
        int b = plane >> 8, c = plane & 255;
        float fw = attn[b * 512 + c];
        float mw = attn[b * 512 + 256 + c];
        float4 f = f4[i];
        float4 m = m4[i];
        float4 o;
        o.x = fmaf(fw, f.x, mw * m.x);
        o.y = fmaf(fw, f.y, mw * m.y);
        o.z = fmaf(fw, f.z, mw * m.z);
        o.w = fmaf(fw, f.w, mw * m.w);
        o4[i] = o;
    }
}

extern "C" void kernel_launch(void* const* d_in, const int* in_sizes, int n_in,
                              void* d_out, int out_size, void* d_ws, size_t ws_size,
                              hipStream_t stream) {
    const float* fft   = (const float*)d_in[0];
    const float* multi = (const float*)d_in[1];
    const float* w1    = (const float*)d_in[2];   // [64][512]
    const float* w2    = (const float*)d_in[3];   // [512][64]
    float* out = (float*)d_out;

    float* pooled = (float*)d_ws;                 // [16][512]
    float* h      = pooled + NB * 512;            // [16][64]
    float* attn   = h + NB * 64;                  // [16][512]

    pool_kernel<<<4096, 256, 0, stream>>>(fft, multi, pooled);
    mlp1_kernel<<<256, 256, 0, stream>>>(pooled, w1, h);
    mlp2_kernel<<<2048, 256, 0, stream>>>(h, w2, attn);
    apply_kernel<<<2048, 256, 0, stream>>>(fft, multi, attn, out);
}